// Round 7
// baseline (17713.361 us; speedup 1.0000x reference)
//
#include <hip/hip_runtime.h>
#include <math.h>

#define T_STEPS 4096
#define RES     2048
#define NF      8
#define NR      8
#define K_WG    512      // 512 single-wave WGs; each wave owns 4 columns
#define WTHR    64       // k_recur block = 1 wave
#define NTHR    256      // helper-kernel block size
#define SENTINEL 2.0f    // reachable |x| < 1 strictly; 2.0 is unreachable
#define VALID_MASK 0x7fffffffu
#define VALID_LIM  0x3f800000u   // abs-bits < 1.0f  <=> valid; sentinel 2.0f fails
#define DBLK 32          // drive block: steps per batched drive load

typedef unsigned long long u64;
typedef unsigned int       u32;

// DPP-accelerated add: x += x from lane given by ctrl (VALU-speed cross-lane).
#define DPP_ADD(x, ctrl)                                                      \
    x += __int_as_float(__builtin_amdgcn_mov_dpp(__float_as_int(x),           \
                                                 (ctrl), 0xf, 0xf, true))
#define DPP_XOR1 0xB1    // quad_perm [1,0,3,2]
#define DPP_XOR2 0x4E    // quad_perm [2,3,0,1]
#define DPP_ROR4 0x124   // row_ror:4 (row of 16)
#define DPP_ROR8 0x128   // row_ror:8

// ---------------------------------------------------------------------------
// drive[t][j] = Win[0][j] + sum_f inp[t][f] * Win[1+f][j]
__global__ void k_drive(const float* __restrict__ inp, const float* __restrict__ Win,
                        float* __restrict__ drive) {
    int idx = blockIdx.x * blockDim.x + threadIdx.x;   // [0, T*RES)
    int t = idx >> 11;
    int j = idx & (RES - 1);
    float d = Win[j];
#pragma unroll
    for (int f = 0; f < NF; ++f)
        d += inp[t * NF + f] * Win[(1 + f) * RES + j];
    drive[idx] = d;
}

// ---------------------------------------------------------------------------
// X[0][:] = 0 (initial state, valid); X[1..T][:] = SENTINEL (unwritten)
__global__ void k_init(float* __restrict__ X) {
    int tid = threadIdx.x + blockIdx.x * blockDim.x;
    int stride = blockDim.x * gridDim.x;
    const int total = (T_STEPS + 1) * RES;
    for (int i = tid; i < total; i += stride)
        X[i] = (i < RES) ? 0.f : SENTINEL;
}

// ---------------------------------------------------------------------------
// Persistent dataflow recurrence -- independent single-wave workgroups.
// r6 landed 1.545us/step; ~1.2us of it is publish->visibility->sample with
// poll RT ~600ns (sampling adds ~1.5RT). This round attacks the two pieces
// under our control:
//  - TWO staggered poll sweeps in flight (P checked while Q outstanding):
//    every check waits vmcnt(16), never a full drain -> sampling period
//    ~RT/2, expected detect delay 1.5RT -> 1.25RT.
//  - DPP reduce: quad_perm xor1/xor2 + row_ror 4/8 (VALU-speed) give each
//    lane its row-of-16 sum; one parallel 3-shuffle gather sums the 4 rows.
//    Replaces 7 serial DS shuffles (~100ns) with ~40ns, and publish now
//    issues BEFORE the next-row pre-sweep. Publish latency gates every
//    other wave's detect, so this is chip-wide.
//
// Correctness structure unchanged: row 0 seeded by k_init, per-location
// sentinel polling, relaxed agent-scope ops, 512 single-wave WGs resident.
__global__ __launch_bounds__(WTHR, 1) void k_recur(
        const float* __restrict__ W, const float* __restrict__ drive,
        float* __restrict__ X) {
    const int lane = threadIdx.x & 63;
    const int g    = blockIdx.x;              // [0, 512)
    const int c0   = g * 4;                   // this wave's 4 output columns

    // W fragment matching register-row ownership:
    // Wr[2i] = W[2*lane+128i][c0..c0+4), Wr[2i+1] = W[2*lane+1+128i][c0..c0+4)
    float4 Wr[32];
#pragma unroll
    for (int i = 0; i < 16; ++i) {
        size_t r0 = (size_t)(2 * lane + 128 * i);
        Wr[2 * i]     = *reinterpret_cast<const float4*>(&W[r0 * RES + c0]);
        Wr[2 * i + 1] = *reinterpret_cast<const float4*>(&W[(r0 + 1) * RES + c0]);
    }
    // Pin: block the compiler from sinking/rematerializing the loads inside
    // the t-loop (prior failure mode: W re-streamed from LLC every step).
#pragma unroll
    for (int i = 0; i < 32; ++i)
        asm volatile("" : "+v"(Wr[i].x), "+v"(Wr[i].y), "+v"(Wr[i].z), "+v"(Wr[i].w));

    float xprev = 0.f;                        // own columns' old x; X[0][:] == 0

    // Batched drive: lane L's u64 covers block-step s=L>>1, cols c0+(L&1)*2+{0,1}.
    auto drv_addr = [&](int tb) {
        return reinterpret_cast<const u64*>(
                   &drive[(size_t)(tb + (lane >> 1)) * RES + c0 + (lane & 1) * 2]);
    };
    u64 dcur = *drv_addr(0);                  // block [0,32)
    u64 dnxt = *drv_addr(DBLK);               // block [32,64)

    // Double-buffered poll sweeps. Lane l's u64 i covers floats {2l+128i, 2l+1+128i}.
    u64 xp[16], xq[16];
    {
        const u64* r0 = reinterpret_cast<const u64*>(X);
#pragma unroll
        for (int i = 0; i < 16; ++i)
            xp[i] = __hip_atomic_load(&r0[i * 64 + lane],
                                      __ATOMIC_RELAXED, __HIP_MEMORY_SCOPE_AGENT);
    }

    for (int t = 0; t < T_STEPS; ++t) {
        const u64* xrow64 = reinterpret_cast<const u64*>(X + (size_t)t * RES);

        // Stagger: issue Q behind the pre-issued P.
#pragma unroll
        for (int i = 0; i < 16; ++i)
            xq[i] = __hip_atomic_load(&xrow64[i * 64 + lane],
                                      __ATOMIC_RELAXED, __HIP_MEMORY_SCOPE_AGENT);

        // Detect: alternate checks of P and Q; each check's implicit wait is
        // vmcnt(16) (the other sweep stays outstanding) -> sampling ~RT/2.
        int spins = 0;
        bool useQ = false;
        for (;;) {
            {   // check P
                u32 m = 0;
#pragma unroll
                for (int i = 0; i < 16; ++i) {
                    u32 lo = (u32)(xp[i])       & VALID_MASK;
                    u32 hi = (u32)(xp[i] >> 32) & VALID_MASK;
                    u32 mx = lo > hi ? lo : hi;
                    m = m > mx ? m : mx;
                }
                if (__all(m < VALID_LIM)) break;
            }
#pragma unroll
            for (int i = 0; i < 16; ++i)       // reissue P (now newest)
                xp[i] = __hip_atomic_load(&xrow64[i * 64 + lane],
                                          __ATOMIC_RELAXED, __HIP_MEMORY_SCOPE_AGENT);
            {   // check Q (older than P's reissue -> vmcnt(16))
                u32 m = 0;
#pragma unroll
                for (int i = 0; i < 16; ++i) {
                    u32 lo = (u32)(xq[i])       & VALID_MASK;
                    u32 hi = (u32)(xq[i] >> 32) & VALID_MASK;
                    u32 mx = lo > hi ? lo : hi;
                    m = m > mx ? m : mx;
                }
                if (__all(m < VALID_LIM)) { useQ = true; break; }
            }
#pragma unroll
            for (int i = 0; i < 16; ++i)       // reissue Q
                xq[i] = __hip_atomic_load(&xrow64[i * 64 + lane],
                                          __ATOMIC_RELAXED, __HIP_MEMORY_SCOPE_AGENT);
            if (++spins > 32) __builtin_amdgcn_s_sleep(1);   // ramp throttle only
        }
        if (useQ) {                            // normalize: wave-uniform branch,
#pragma unroll                                 // 32 v_mov (~13ns), rare path cost
            for (int i = 0; i < 16; ++i) xp[i] = xq[i];
        }

        // Extract this step's drive for lanes 0-3 from the block registers.
        const int s = t & (DBLK - 1);
        float dr;
        {
            float lo = __uint_as_float((u32)dcur);
            float hi = __uint_as_float((u32)(dcur >> 32));
            int   src = 2 * s + ((lane & 3) >> 1);
            float v0 = __shfl(lo, src, 64);
            float v1 = __shfl(hi, src, 64);
            dr = (lane & 1) ? v1 : v0;                   // lanes 0-3: cols c0+0..3
        }
        if (s == DBLK - 1 && t + 1 < T_STEPS) {
            dcur = dnxt;
            int tb2 = t + 1 + DBLK;
            if (tb2 < T_STEPS) dnxt = *drv_addr(tb2);
        }

        // z[c0+j] = sum over this lane's 32 owned rows, straight from regs.
        float a0 = 0.f, a1 = 0.f, a2 = 0.f, a3 = 0.f;
#pragma unroll
        for (int i = 0; i < 16; ++i) {
            float xlo = __uint_as_float((u32)xp[i]);
            float xhi = __uint_as_float((u32)(xp[i] >> 32));
            float4 wl = Wr[2 * i];
            float4 wh = Wr[2 * i + 1];
            a0 = fmaf(xlo, wl.x, a0); a0 = fmaf(xhi, wh.x, a0);
            a1 = fmaf(xlo, wl.y, a1); a1 = fmaf(xhi, wh.y, a1);
            a2 = fmaf(xlo, wl.z, a2); a2 = fmaf(xhi, wh.z, a2);
            a3 = fmaf(xlo, wl.w, a3); a3 = fmaf(xhi, wh.w, a3);
        }

        // DPP reduce: each a_j summed across its row-of-16 (VALU-speed).
        DPP_ADD(a0, DPP_XOR1); DPP_ADD(a1, DPP_XOR1);
        DPP_ADD(a2, DPP_XOR1); DPP_ADD(a3, DPP_XOR1);
        DPP_ADD(a0, DPP_XOR2); DPP_ADD(a1, DPP_XOR2);
        DPP_ADD(a2, DPP_XOR2); DPP_ADD(a3, DPP_XOR2);
        DPP_ADD(a0, DPP_ROR4); DPP_ADD(a1, DPP_ROR4);
        DPP_ADD(a2, DPP_ROR4); DPP_ADD(a3, DPP_ROR4);
        DPP_ADD(a0, DPP_ROR8); DPP_ADD(a1, DPP_ROR8);
        DPP_ADD(a2, DPP_ROR8); DPP_ADD(a3, DPP_ROR8);
        // Lane l picks its column's row-sum; 3 parallel shuffles gather the
        // other 3 rows ((lane+16k)&3 == lane&3, so sources pick same column).
        float ac = (lane & 1) ? ((lane & 2) ? a3 : a1)
                              : ((lane & 2) ? a2 : a0);
        float t1 = __shfl(ac, (lane + 16) & 63, 64);
        float t2 = __shfl(ac, (lane + 32) & 63, 64);
        float t3 = __shfl(ac, (lane + 48) & 63, 64);
        float p  = ac + t1 + t2 + t3;          // lane l: full sum for col c0+(l&3)

        if (lane < 4) {                        // lane l holds column c0+l
            float ss = dr + p;
            float e  = __expf(2.0f * ss);      // v_exp_f32 fast path
            float th = 1.0f - 2.0f * __builtin_amdgcn_rcpf(e + 1.0f);
            float xn = 0.7f * xprev + 0.3f * th;
            // Publish FIRST (gates every other wave's detect), then pre-issue.
            __hip_atomic_store(&X[(size_t)(t + 1) * RES + c0 + lane], xn,
                               __ATOMIC_RELAXED, __HIP_MEMORY_SCOPE_AGENT);
            xprev = xn;
        }

        // Pre-issue next row's P sweep (checked at next loop top).
        {
            const u64* nrow64 = reinterpret_cast<const u64*>(
                                    X + (size_t)(t + 1) * RES);
#pragma unroll
            for (int i = 0; i < 16; ++i)
                xp[i] = __hip_atomic_load(&nrow64[i * 64 + lane],
                                          __ATOMIC_RELAXED, __HIP_MEMORY_SCOPE_AGENT);
        }
    }
}

// ---------------------------------------------------------------------------
// Y[t][r] = Wout[0][r] + sum_f inp[t][f]*Wout[1+f][r] + sum_j X[t+1][j]*Wout[9+j][r]
__global__ void k_readout(const float* __restrict__ inp, const float* __restrict__ Wout,
                          const float* __restrict__ X, float* __restrict__ Y) {
    int t   = blockIdx.x;
    int tid = threadIdx.x;
    int r   = tid & (NR - 1);
    int gph = tid >> 3;                    // 32 groups
    const float* x = X + (size_t)(t + 1) * RES;
    float p = 0.f;
#pragma unroll 4
    for (int m = 0; m < RES / 32; ++m) {
        int j = gph * (RES / 32) + m;
        p += x[j] * Wout[(size_t)(1 + NF + j) * NR + r];
    }
    __shared__ float red[NTHR];
    red[tid] = p;
    __syncthreads();
    for (int s = NTHR / 2; s >= NR; s >>= 1) {
        if (tid < s) red[tid] += red[tid + s];
        __syncthreads();
    }
    if (tid < NR) {
        float y = Wout[tid];
#pragma unroll
        for (int f = 0; f < NF; ++f)
            y += inp[t * NF + f] * Wout[(1 + f) * NR + tid];
        Y[t * NR + tid] = y + red[tid];
    }
}

// ---------------------------------------------------------------------------
extern "C" void kernel_launch(void* const* d_in, const int* in_sizes, int n_in,
                              void* d_out, int out_size, void* d_ws, size_t ws_size,
                              hipStream_t stream) {
    const float* inp  = (const float*)d_in[0];   // (T, 8)
    const float* Win  = (const float*)d_in[1];   // (9, 2048)
    const float* W    = (const float*)d_in[2];   // (2048, 2048)
    const float* Wout = (const float*)d_in[3];   // (2057, 8)
    float* Y = (float*)d_out;                    // (T, 8)

    float* drive = (float*)d_ws;                            // 32 MB
    float* X     = drive + (size_t)T_STEPS * RES;           // 32 MB + 8 KB

    k_init<<<2048, NTHR, 0, stream>>>(X);
    k_drive<<<(T_STEPS * RES) / NTHR, NTHR, 0, stream>>>(inp, Win, drive);
    k_recur<<<K_WG, WTHR, 0, stream>>>(W, drive, X);
    k_readout<<<T_STEPS, NTHR, 0, stream>>>(inp, Wout, X, Y);
}

// Round 8
// 14154.131 us; speedup vs baseline: 1.2515x; 1.2515x over previous
//
#include <hip/hip_runtime.h>
#include <math.h>

#define T_STEPS 4096
#define RES     2048
#define NF      8
#define NR      8
#define K_WG    512      // 512 single-wave WGs; each wave owns 4 columns
#define WTHR    64       // k_recur block = 1 wave
#define NTHR    256      // helper-kernel block size
#define SENTINEL 2.0f    // reachable |x| < 1 strictly; 2.0 is unreachable
#define VALID_MASK 0x7fffffffu
#define VALID_LIM  0x3f800000u   // abs-bits < 1.0f  <=> valid; sentinel 2.0f fails
#define DBLK 32          // drive block: steps per batched drive load

typedef unsigned long long u64;
typedef unsigned int       u32;

// DPP-accelerated add: x += x from lane given by ctrl (VALU-speed cross-lane).
// Numerics verified on-harness in round 7 (absmax 0.00098, passed).
#define DPP_ADD(x, ctrl)                                                      \
    x += __int_as_float(__builtin_amdgcn_mov_dpp(__float_as_int(x),           \
                                                 (ctrl), 0xf, 0xf, true))
#define DPP_XOR1 0xB1    // quad_perm [1,0,3,2]
#define DPP_XOR2 0x4E    // quad_perm [2,3,0,1]
#define DPP_ROR4 0x124   // row_ror:4 (row of 16)
#define DPP_ROR8 0x128   // row_ror:8

// ---------------------------------------------------------------------------
// drive[t][j] = Win[0][j] + sum_f inp[t][f] * Win[1+f][j]
__global__ void k_drive(const float* __restrict__ inp, const float* __restrict__ Win,
                        float* __restrict__ drive) {
    int idx = blockIdx.x * blockDim.x + threadIdx.x;   // [0, T*RES)
    int t = idx >> 11;
    int j = idx & (RES - 1);
    float d = Win[j];
#pragma unroll
    for (int f = 0; f < NF; ++f)
        d += inp[t * NF + f] * Win[(1 + f) * RES + j];
    drive[idx] = d;
}

// ---------------------------------------------------------------------------
// X[0][:] = 0 (initial state, valid); X[1..T][:] = SENTINEL (unwritten)
__global__ void k_init(float* __restrict__ X) {
    int tid = threadIdx.x + blockIdx.x * blockDim.x;
    int stride = blockDim.x * gridDim.x;
    const int total = (T_STEPS + 1) * RES;
    for (int i = tid; i < total; i += stride)
        X[i] = (i < RES) ? 0.f : SENTINEL;
}

// ---------------------------------------------------------------------------
// Persistent dataflow recurrence -- independent single-wave workgroups.
// Evidence chain: poll bytes cheap to REDUCE (r2) but doubling outstanding
// poll loads congests the coherence point nonlinearly (r7: 2 staggered
// sweeps -> FETCH x2, dur x2.8). Single pipelined sweep (r6 structure) is
// the polling sweet spot. This round keeps r6 polling EXACTLY and applies
// only the (r7-verified-numerically) serial-path cut:
//  - DPP reduce: quad_perm xor1/xor2 + row_ror 4/8 (VALU-speed, no DS
//    latency) + 3 parallel shuffles, replacing 7 SERIAL ds_bpermutes
//    (~100ns -> ~40ns between FMA end and publish);
//  - publish BEFORE the next-row pre-issue sweep. Every wave's publish
//    gates all other waves' detect -> chip-wide critical-chain cut.
//
// Correctness structure unchanged: row 0 seeded by k_init, per-location
// sentinel polling, relaxed agent-scope ops, 512 single-wave WGs resident.
__global__ __launch_bounds__(WTHR, 1) void k_recur(
        const float* __restrict__ W, const float* __restrict__ drive,
        float* __restrict__ X) {
    const int lane = threadIdx.x & 63;
    const int g    = blockIdx.x;              // [0, 512)
    const int c0   = g * 4;                   // this wave's 4 output columns

    // W fragment matching register-row ownership:
    // Wr[2i] = W[2*lane+128i][c0..c0+4), Wr[2i+1] = W[2*lane+1+128i][c0..c0+4)
    float4 Wr[32];
#pragma unroll
    for (int i = 0; i < 16; ++i) {
        size_t r0 = (size_t)(2 * lane + 128 * i);
        Wr[2 * i]     = *reinterpret_cast<const float4*>(&W[r0 * RES + c0]);
        Wr[2 * i + 1] = *reinterpret_cast<const float4*>(&W[(r0 + 1) * RES + c0]);
    }
    // Pin: block the compiler from sinking/rematerializing the loads inside
    // the t-loop (prior failure mode: W re-streamed from LLC every step).
#pragma unroll
    for (int i = 0; i < 32; ++i)
        asm volatile("" : "+v"(Wr[i].x), "+v"(Wr[i].y), "+v"(Wr[i].z), "+v"(Wr[i].w));

    float xprev = 0.f;                        // own columns' old x; X[0][:] == 0

    // Batched drive: lane L's u64 covers block-step s=L>>1, cols c0+(L&1)*2+{0,1}.
    auto drv_addr = [&](int tb) {
        return reinterpret_cast<const u64*>(
                   &drive[(size_t)(tb + (lane >> 1)) * RES + c0 + (lane & 1) * 2]);
    };
    u64 dcur = *drv_addr(0);                  // block [0,32)
    u64 dnxt = *drv_addr(DBLK);               // block [32,64)

    // Single pipelined poll sweep (r6 structure). Lane l's u64 i covers
    // floats {2l+128i, 2l+1+128i}.
    u64 xv[16];
    {
        const u64* r0 = reinterpret_cast<const u64*>(X);
#pragma unroll
        for (int i = 0; i < 16; ++i)
            xv[i] = __hip_atomic_load(&r0[i * 64 + lane],
                                      __ATOMIC_RELAXED, __HIP_MEMORY_SCOPE_AGENT);
    }

    for (int t = 0; t < T_STEPS; ++t) {
        const u64* xrow64 = reinterpret_cast<const u64*>(X + (size_t)t * RES);

        // Detect: first eval consumes the pre-issued sweep; retries reload.
        int spins = 0;
        for (;;) {
            u32 m = 0;
#pragma unroll
            for (int i = 0; i < 16; ++i) {
                u32 lo = (u32)(xv[i])       & VALID_MASK;
                u32 hi = (u32)(xv[i] >> 32) & VALID_MASK;
                u32 mx = lo > hi ? lo : hi;
                m = m > mx ? m : mx;
            }
            if (__all(m < VALID_LIM)) break;  // full row verified across the wave
            if (++spins > 64) __builtin_amdgcn_s_sleep(1);   // ramp throttle only
#pragma unroll
            for (int i = 0; i < 16; ++i)
                xv[i] = __hip_atomic_load(&xrow64[i * 64 + lane],
                                          __ATOMIC_RELAXED, __HIP_MEMORY_SCOPE_AGENT);
        }

        // Extract this step's drive for lanes 0-3 from the block registers.
        const int s = t & (DBLK - 1);
        float dr;
        {
            float lo = __uint_as_float((u32)dcur);
            float hi = __uint_as_float((u32)(dcur >> 32));
            int   src = 2 * s + ((lane & 3) >> 1);       // clamped for lanes >= 4
            float v0 = __shfl(lo, src, 64);
            float v1 = __shfl(hi, src, 64);
            dr = (lane & 1) ? v1 : v0;                   // lanes 0-3: cols c0+0..3
        }
        if (s == DBLK - 1 && t + 1 < T_STEPS) {
            dcur = dnxt;                                 // data long since landed
            int tb2 = t + 1 + DBLK;
            if (tb2 < T_STEPS) dnxt = *drv_addr(tb2);
        }

        // z[c0+j] = sum over this lane's 32 owned rows, straight from regs.
        float a0 = 0.f, a1 = 0.f, a2 = 0.f, a3 = 0.f;
#pragma unroll
        for (int i = 0; i < 16; ++i) {
            float xlo = __uint_as_float((u32)xv[i]);
            float xhi = __uint_as_float((u32)(xv[i] >> 32));
            float4 wl = Wr[2 * i];
            float4 wh = Wr[2 * i + 1];
            a0 = fmaf(xlo, wl.x, a0); a0 = fmaf(xhi, wh.x, a0);
            a1 = fmaf(xlo, wl.y, a1); a1 = fmaf(xhi, wh.y, a1);
            a2 = fmaf(xlo, wl.z, a2); a2 = fmaf(xhi, wh.z, a2);
            a3 = fmaf(xlo, wl.w, a3); a3 = fmaf(xhi, wh.w, a3);
        }

        // DPP reduce: each a_j summed across its row-of-16 (VALU-speed,
        // no serial DS-shuffle latency).
        DPP_ADD(a0, DPP_XOR1); DPP_ADD(a1, DPP_XOR1);
        DPP_ADD(a2, DPP_XOR1); DPP_ADD(a3, DPP_XOR1);
        DPP_ADD(a0, DPP_XOR2); DPP_ADD(a1, DPP_XOR2);
        DPP_ADD(a2, DPP_XOR2); DPP_ADD(a3, DPP_XOR2);
        DPP_ADD(a0, DPP_ROR4); DPP_ADD(a1, DPP_ROR4);
        DPP_ADD(a2, DPP_ROR4); DPP_ADD(a3, DPP_ROR4);
        DPP_ADD(a0, DPP_ROR8); DPP_ADD(a1, DPP_ROR8);
        DPP_ADD(a2, DPP_ROR8); DPP_ADD(a3, DPP_ROR8);
        // Lane l picks its column's row-of-16 sum; 3 parallel shuffles gather
        // the other 3 rows ((lane+16k)&3 == lane&3 -> same column sources).
        float ac = (lane & 1) ? ((lane & 2) ? a3 : a1)
                              : ((lane & 2) ? a2 : a0);
        float t1 = __shfl(ac, (lane + 16) & 63, 64);
        float t2 = __shfl(ac, (lane + 32) & 63, 64);
        float t3 = __shfl(ac, (lane + 48) & 63, 64);
        float p  = ac + t1 + t2 + t3;          // lane l: full sum for col c0+(l&3)

        if (lane < 4) {                        // lane l holds column c0+l
            float ss = dr + p;
            float e  = __expf(2.0f * ss);      // v_exp_f32 fast path
            float th = 1.0f - 2.0f * __builtin_amdgcn_rcpf(e + 1.0f);
            float xn = 0.7f * xprev + 0.3f * th;
            // Publish FIRST (gates every other wave's detect), then pre-issue.
            __hip_atomic_store(&X[(size_t)(t + 1) * RES + c0 + lane], xn,
                               __ATOMIC_RELAXED, __HIP_MEMORY_SCOPE_AGENT);
            xprev = xn;
        }

        // Pre-issue next row's sweep (checked at next loop top).
        {
            const u64* nrow64 = reinterpret_cast<const u64*>(
                                    X + (size_t)(t + 1) * RES);
#pragma unroll
            for (int i = 0; i < 16; ++i)
                xv[i] = __hip_atomic_load(&nrow64[i * 64 + lane],
                                          __ATOMIC_RELAXED, __HIP_MEMORY_SCOPE_AGENT);
        }
    }
}

// ---------------------------------------------------------------------------
// Y[t][r] = Wout[0][r] + sum_f inp[t][f]*Wout[1+f][r] + sum_j X[t+1][j]*Wout[9+j][r]
__global__ void k_readout(const float* __restrict__ inp, const float* __restrict__ Wout,
                          const float* __restrict__ X, float* __restrict__ Y) {
    int t   = blockIdx.x;
    int tid = threadIdx.x;
    int r   = tid & (NR - 1);
    int gph = tid >> 3;                    // 32 groups
    const float* x = X + (size_t)(t + 1) * RES;
    float p = 0.f;
#pragma unroll 4
    for (int m = 0; m < RES / 32; ++m) {
        int j = gph * (RES / 32) + m;
        p += x[j] * Wout[(size_t)(1 + NF + j) * NR + r];
    }
    __shared__ float red[NTHR];
    red[tid] = p;
    __syncthreads();
    for (int s = NTHR / 2; s >= NR; s >>= 1) {
        if (tid < s) red[tid] += red[tid + s];
        __syncthreads();
    }
    if (tid < NR) {
        float y = Wout[tid];
#pragma unroll
        for (int f = 0; f < NF; ++f)
            y += inp[t * NF + f] * Wout[(1 + f) * NR + tid];
        Y[t * NR + tid] = y + red[tid];
    }
}

// ---------------------------------------------------------------------------
extern "C" void kernel_launch(void* const* d_in, const int* in_sizes, int n_in,
                              void* d_out, int out_size, void* d_ws, size_t ws_size,
                              hipStream_t stream) {
    const float* inp  = (const float*)d_in[0];   // (T, 8)
    const float* Win  = (const float*)d_in[1];   // (9, 2048)
    const float* W    = (const float*)d_in[2];   // (2048, 2048)
    const float* Wout = (const float*)d_in[3];   // (2057, 8)
    float* Y = (float*)d_out;                    // (T, 8)

    float* drive = (float*)d_ws;                            // 32 MB
    float* X     = drive + (size_t)T_STEPS * RES;           // 32 MB + 8 KB

    k_init<<<2048, NTHR, 0, stream>>>(X);
    k_drive<<<(T_STEPS * RES) / NTHR, NTHR, 0, stream>>>(inp, Win, drive);
    k_recur<<<K_WG, WTHR, 0, stream>>>(W, drive, X);
    k_readout<<<T_STEPS, NTHR, 0, stream>>>(inp, Wout, X, Y);
}

// Round 10
// 6235.936 us; speedup vs baseline: 2.8405x; 2.2698x over previous
//
#include <hip/hip_runtime.h>
#include <math.h>

#define T_STEPS 4096
#define RES     2048
#define NF      8
#define NR      8
#define K_WG    512      // 512 single-wave WGs; each wave owns 4 columns
#define WTHR    64       // k_recur block = 1 wave
#define NTHR    256      // helper-kernel block size
#define SENTINEL 2.0f    // reachable |x| < 1 strictly; 2.0 is unreachable
#define VALID_MASK 0x7fffffffu
#define VALID_LIM  0x3f800000u   // abs-bits < 1.0f  <=> valid; sentinel 2.0f fails
#define DBLK 32          // drive block: steps per batched drive load

typedef unsigned long long u64;
typedef unsigned int       u32;

// DPP-accelerated add: x += x from lane given by ctrl (VALU-speed cross-lane).
// Numerics verified on-harness in rounds 7 and 8 (absmax 0.00098, passed).
#define DPP_ADD(x, ctrl)                                                      \
    x += __int_as_float(__builtin_amdgcn_mov_dpp(__float_as_int(x),           \
                                                 (ctrl), 0xf, 0xf, true))
#define DPP_XOR1 0xB1    // quad_perm [1,0,3,2]
#define DPP_XOR2 0x4E    // quad_perm [2,3,0,1]
#define DPP_ROR4 0x124   // row_ror:4 (row of 16)
#define DPP_ROR8 0x128   // row_ror:8

// ---------------------------------------------------------------------------
// drive[t][j] = Win[0][j] + sum_f inp[t][f] * Win[1+f][j]
__global__ void k_drive(const float* __restrict__ inp, const float* __restrict__ Win,
                        float* __restrict__ drive) {
    int idx = blockIdx.x * blockDim.x + threadIdx.x;   // [0, T*RES)
    int t = idx >> 11;
    int j = idx & (RES - 1);
    float d = Win[j];
#pragma unroll
    for (int f = 0; f < NF; ++f)
        d += inp[t * NF + f] * Win[(1 + f) * RES + j];
    drive[idx] = d;
}

// ---------------------------------------------------------------------------
// X[0][:] = 0 (initial state, valid); X[1..T][:] = SENTINEL (unwritten)
__global__ void k_init(float* __restrict__ X) {
    int tid = threadIdx.x + blockIdx.x * blockDim.x;
    int stride = blockDim.x * gridDim.x;
    const int total = (T_STEPS + 1) * RES;
    for (int i = tid; i < total; i += stride)
        X[i] = (i < RES) ? 0.f : SENTINEL;
}

// ---------------------------------------------------------------------------
// Persistent dataflow recurrence -- independent single-wave workgroups.
// Evidence chain:
//  r2: poll bytes cheap to reduce;  r3: poll-iteration cost real;
//  r4: post-detect serial path real; r5: drive-prefetch vmcnt poison innocent;
//  r6: WG-cooperative stage was overhead (delete -> 1.545us/step);
//  r7: doubling outstanding poll sweeps congests coherence point (x2.8 dur);
//  r8: publish issued BEFORE pre-issue sweep poisons detect -- vmcnt retires
//      IN ORDER, so the older store ack gates the newer loads every step.
// Ordering law: the publish store must be the NEWEST VMEM op at detect time.
// This kernel = r6 structure exactly (FMA -> pre-issue -> reduce -> publish
// LAST) with only the DPP reduce swapped in for the 7 serial DS shuffles.
__global__ __launch_bounds__(WTHR, 1) void k_recur(
        const float* __restrict__ W, const float* __restrict__ drive,
        float* __restrict__ X) {
    const int lane = threadIdx.x & 63;
    const int g    = blockIdx.x;              // [0, 512)
    const int c0   = g * 4;                   // this wave's 4 output columns

    // W fragment matching register-row ownership:
    // Wr[2i] = W[2*lane+128i][c0..c0+4), Wr[2i+1] = W[2*lane+1+128i][c0..c0+4)
    float4 Wr[32];
#pragma unroll
    for (int i = 0; i < 16; ++i) {
        size_t r0 = (size_t)(2 * lane + 128 * i);
        Wr[2 * i]     = *reinterpret_cast<const float4*>(&W[r0 * RES + c0]);
        Wr[2 * i + 1] = *reinterpret_cast<const float4*>(&W[(r0 + 1) * RES + c0]);
    }
    // Pin: block the compiler from sinking/rematerializing the loads inside
    // the t-loop (prior failure mode: W re-streamed from LLC every step).
#pragma unroll
    for (int i = 0; i < 32; ++i)
        asm volatile("" : "+v"(Wr[i].x), "+v"(Wr[i].y), "+v"(Wr[i].z), "+v"(Wr[i].w));

    float xprev = 0.f;                        // own columns' old x; X[0][:] == 0

    // Batched drive: lane L's u64 covers block-step s=L>>1, cols c0+(L&1)*2+{0,1}.
    auto drv_addr = [&](int tb) {
        return reinterpret_cast<const u64*>(
                   &drive[(size_t)(tb + (lane >> 1)) * RES + c0 + (lane & 1) * 2]);
    };
    u64 dcur = *drv_addr(0);                  // block [0,32)
    u64 dnxt = *drv_addr(DBLK);               // block [32,64)

    // Single pipelined poll sweep (r6 structure). Lane l's u64 i covers
    // floats {2l+128i, 2l+1+128i}.
    u64 xv[16];
    {
        const u64* r0 = reinterpret_cast<const u64*>(X);
#pragma unroll
        for (int i = 0; i < 16; ++i)
            xv[i] = __hip_atomic_load(&r0[i * 64 + lane],
                                      __ATOMIC_RELAXED, __HIP_MEMORY_SCOPE_AGENT);
    }

    for (int t = 0; t < T_STEPS; ++t) {
        const u64* xrow64 = reinterpret_cast<const u64*>(X + (size_t)t * RES);

        // Detect: first eval consumes the pre-issued sweep; retries reload.
        int spins = 0;
        for (;;) {
            u32 m = 0;
#pragma unroll
            for (int i = 0; i < 16; ++i) {
                u32 lo = (u32)(xv[i])       & VALID_MASK;
                u32 hi = (u32)(xv[i] >> 32) & VALID_MASK;
                u32 mx = lo > hi ? lo : hi;
                m = m > mx ? m : mx;
            }
            if (__all(m < VALID_LIM)) break;  // full row verified across the wave
            if (++spins > 64) __builtin_amdgcn_s_sleep(1);   // ramp throttle only
#pragma unroll
            for (int i = 0; i < 16; ++i)
                xv[i] = __hip_atomic_load(&xrow64[i * 64 + lane],
                                          __ATOMIC_RELAXED, __HIP_MEMORY_SCOPE_AGENT);
        }

        // Extract this step's drive for lanes 0-3 from the block registers.
        const int s = t & (DBLK - 1);
        float dr;
        {
            float lo = __uint_as_float((u32)dcur);
            float hi = __uint_as_float((u32)(dcur >> 32));
            int   src = 2 * s + ((lane & 3) >> 1);       // clamped for lanes >= 4
            float v0 = __shfl(lo, src, 64);
            float v1 = __shfl(hi, src, 64);
            dr = (lane & 1) ? v1 : v0;                   // lanes 0-3: cols c0+0..3
        }
        if (s == DBLK - 1 && t + 1 < T_STEPS) {
            dcur = dnxt;                                 // data long since landed
            int tb2 = t + 1 + DBLK;
            if (tb2 < T_STEPS) dnxt = *drv_addr(tb2);
        }

        // z[c0+j] = sum over this lane's 32 owned rows, straight from regs.
        float a0 = 0.f, a1 = 0.f, a2 = 0.f, a3 = 0.f;
#pragma unroll
        for (int i = 0; i < 16; ++i) {
            float xlo = __uint_as_float((u32)xv[i]);
            float xhi = __uint_as_float((u32)(xv[i] >> 32));
            float4 wl = Wr[2 * i];
            float4 wh = Wr[2 * i + 1];
            a0 = fmaf(xlo, wl.x, a0); a0 = fmaf(xhi, wh.x, a0);
            a1 = fmaf(xlo, wl.y, a1); a1 = fmaf(xhi, wh.y, a1);
            a2 = fmaf(xlo, wl.z, a2); a2 = fmaf(xhi, wh.z, a2);
            a3 = fmaf(xlo, wl.w, a3); a3 = fmaf(xhi, wh.w, a3);
        }

        // Pre-issue next row's sweep NOW (xv dead): these loads must be OLDER
        // than the publish store so detect never waits on the store ack
        // (r8 lesson -- in-order vmcnt retirement).
        {
            const u64* nrow64 = reinterpret_cast<const u64*>(
                                    X + (size_t)(t + 1) * RES);
#pragma unroll
            for (int i = 0; i < 16; ++i)
                xv[i] = __hip_atomic_load(&nrow64[i * 64 + lane],
                                          __ATOMIC_RELAXED, __HIP_MEMORY_SCOPE_AGENT);
        }

        // DPP reduce: each a_j summed across its row-of-16 (VALU-speed,
        // no serial DS-shuffle latency).
        DPP_ADD(a0, DPP_XOR1); DPP_ADD(a1, DPP_XOR1);
        DPP_ADD(a2, DPP_XOR1); DPP_ADD(a3, DPP_XOR1);
        DPP_ADD(a0, DPP_XOR2); DPP_ADD(a1, DPP_XOR2);
        DPP_ADD(a2, DPP_XOR2); DPP_ADD(a3, DPP_XOR2);
        DPP_ADD(a0, DPP_ROR4); DPP_ADD(a1, DPP_ROR4);
        DPP_ADD(a2, DPP_ROR4); DPP_ADD(a3, DPP_ROR4);
        DPP_ADD(a0, DPP_ROR8); DPP_ADD(a1, DPP_ROR8);
        DPP_ADD(a2, DPP_ROR8); DPP_ADD(a3, DPP_ROR8);
        // Lane l picks its column's row-of-16 sum; 3 parallel shuffles gather
        // the other 3 rows ((lane+16k)&3 == lane&3 -> same column sources).
        float ac = (lane & 1) ? ((lane & 2) ? a3 : a1)
                              : ((lane & 2) ? a2 : a0);
        float t1 = __shfl(ac, (lane + 16) & 63, 64);
        float t2 = __shfl(ac, (lane + 32) & 63, 64);
        float t3 = __shfl(ac, (lane + 48) & 63, 64);
        float p  = ac + t1 + t2 + t3;          // lane l: full sum for col c0+(l&3)

        if (lane < 4) {                        // lane l holds column c0+l
            float ss = dr + p;
            float e  = __expf(2.0f * ss);      // v_exp_f32 fast path
            float th = 1.0f - 2.0f * __builtin_amdgcn_rcpf(e + 1.0f);
            float xn = 0.7f * xprev + 0.3f * th;
            // Publish LAST: newest VMEM op in the queue (r8 ordering law).
            __hip_atomic_store(&X[(size_t)(t + 1) * RES + c0 + lane], xn,
                               __ATOMIC_RELAXED, __HIP_MEMORY_SCOPE_AGENT);
            xprev = xn;
        }
    }
}

// ---------------------------------------------------------------------------
// Y[t][r] = Wout[0][r] + sum_f inp[t][f]*Wout[1+f][r] + sum_j X[t+1][j]*Wout[9+j][r]
__global__ void k_readout(const float* __restrict__ inp, const float* __restrict__ Wout,
                          const float* __restrict__ X, float* __restrict__ Y) {
    int t   = blockIdx.x;
    int tid = threadIdx.x;
    int r   = tid & (NR - 1);
    int gph = tid >> 3;                    // 32 groups
    const float* x = X + (size_t)(t + 1) * RES;
    float p = 0.f;
#pragma unroll 4
    for (int m = 0; m < RES / 32; ++m) {
        int j = gph * (RES / 32) + m;
        p += x[j] * Wout[(size_t)(1 + NF + j) * NR + r];
    }
    __shared__ float red[NTHR];
    red[tid] = p;
    __syncthreads();
    for (int s = NTHR / 2; s >= NR; s >>= 1) {
        if (tid < s) red[tid] += red[tid + s];
        __syncthreads();
    }
    if (tid < NR) {
        float y = Wout[tid];
#pragma unroll
        for (int f = 0; f < NF; ++f)
            y += inp[t * NF + f] * Wout[(1 + f) * NR + tid];
        Y[t * NR + tid] = y + red[tid];
    }
}

// ---------------------------------------------------------------------------
extern "C" void kernel_launch(void* const* d_in, const int* in_sizes, int n_in,
                              void* d_out, int out_size, void* d_ws, size_t ws_size,
                              hipStream_t stream) {
    const float* inp  = (const float*)d_in[0];   // (T, 8)
    const float* Win  = (const float*)d_in[1];   // (9, 2048)
    const float* W    = (const float*)d_in[2];   // (2048, 2048)
    const float* Wout = (const float*)d_in[3];   // (2057, 8)
    float* Y = (float*)d_out;                    // (T, 8)

    float* drive = (float*)d_ws;                            // 32 MB
    float* X     = drive + (size_t)T_STEPS * RES;           // 32 MB + 8 KB

    k_init<<<2048, NTHR, 0, stream>>>(X);
    k_drive<<<(T_STEPS * RES) / NTHR, NTHR, 0, stream>>>(inp, Win, drive);
    k_recur<<<K_WG, WTHR, 0, stream>>>(W, drive, X);
    k_readout<<<T_STEPS, NTHR, 0, stream>>>(inp, Wout, X, Y);
}